// Round 1
// baseline (472.622 us; speedup 1.0000x reference)
//
#include <hip/hip_runtime.h>

constexpr float LN_EPS = 1e-5f;

// ---------------- CSR build ----------------

__global__ __launch_bounds__(256) void k_hist(const int* __restrict__ ei, int* __restrict__ cnt, int E) {
  int e = blockIdx.x * 256 + threadIdx.x;
  if (e < E) atomicAdd(&cnt[ei[E + e]], 1);
}

__global__ __launch_bounds__(256) void k_scan1(const int* __restrict__ in, int* __restrict__ out,
                                               int* __restrict__ bsums, int n) {
  __shared__ int s[256];
  int i = blockIdx.x * 256 + threadIdx.x;
  int v = (i < n) ? in[i] : 0;
  s[threadIdx.x] = v;
  __syncthreads();
  for (int off = 1; off < 256; off <<= 1) {
    int t = (threadIdx.x >= off) ? s[threadIdx.x - off] : 0;
    __syncthreads();
    s[threadIdx.x] += t;
    __syncthreads();
  }
  if (i < n) out[i] = s[threadIdx.x];
  if (threadIdx.x == 255) bsums[blockIdx.x] = s[255];
}

__global__ __launch_bounds__(256) void k_scan2(int* __restrict__ bsums, int nb) {
  __shared__ int s[256];
  int v = (threadIdx.x < nb) ? bsums[threadIdx.x] : 0;
  s[threadIdx.x] = v;
  __syncthreads();
  for (int off = 1; off < 256; off <<= 1) {
    int t = (threadIdx.x >= off) ? s[threadIdx.x - off] : 0;
    __syncthreads();
    s[threadIdx.x] += t;
    __syncthreads();
  }
  if (threadIdx.x < nb) bsums[threadIdx.x] = s[threadIdx.x] - v;  // exclusive
}

__global__ __launch_bounds__(256) void k_scan3(const int* __restrict__ incl, const int* __restrict__ bsums,
                                               int* __restrict__ rowptr, int n) {
  int i = blockIdx.x * 256 + threadIdx.x;
  if (i < n) rowptr[i + 1] = incl[i] + bsums[blockIdx.x];
  if (i == 0) rowptr[0] = 0;
}

__global__ __launch_bounds__(256) void k_fill(const int* __restrict__ ei, const int* __restrict__ rowptr,
                                              int* __restrict__ cursor, int* __restrict__ srclist, int E) {
  int e = blockIdx.x * 256 + threadIdx.x;
  if (e >= E) return;
  int s = ei[e];
  int d = ei[E + e];
  int pos = atomicAdd(&cursor[d], 1);
  srclist[rowptr[d] + pos] = s;
}

// ---------------- fp32 GEMM: Y[M][NCOL] = X[M][128] @ W[128][NCOL] (+bias) (+=Y) ----------------

template <int NCOL>
__global__ __launch_bounds__(256) void k_gemm(const float* __restrict__ X, const float* __restrict__ W,
                                              const float* __restrict__ bias, float* __restrict__ Y,
                                              int M, int accumulate) {
  constexpr int CT = NCOL / 4;   // threads along cols (each owns 4 cols)
  constexpr int RT = 256 / CT;   // threads along rows
  constexpr int RPT = 32 / RT;   // rows per thread
  __shared__ float sW[64][NCOL];
  __shared__ float sX[32][68];   // stride 68: 8 row-readers land on distinct banks
  const int tid = threadIdx.x;
  const int tc = tid % CT;
  const int tr = tid / CT;
  const int row0 = blockIdx.x * 32;
  float acc[RPT][4];
#pragma unroll
  for (int r = 0; r < RPT; ++r)
#pragma unroll
    for (int c = 0; c < 4; ++c) acc[r][c] = 0.f;

  for (int kc = 0; kc < 128; kc += 64) {
    constexpr int WV = 64 * NCOL / 4;
    const float4* Wg = (const float4*)(W + kc * NCOL);
    for (int i = tid; i < WV; i += 256) ((float4*)&sW[0][0])[i] = Wg[i];
    for (int i = tid; i < 32 * 16; i += 256) {
      int rr = i >> 4, cc = i & 15;
      int grow = row0 + rr;
      float4 v = make_float4(0.f, 0.f, 0.f, 0.f);
      if (grow < M) v = *(const float4*)(X + (size_t)grow * 128 + kc + cc * 4);
      *(float4*)&sX[rr][cc * 4] = v;
    }
    __syncthreads();
#pragma unroll 8
    for (int k = 0; k < 64; ++k) {
      float4 w = *(float4*)&sW[k][tc * 4];
#pragma unroll
      for (int r = 0; r < RPT; ++r) {
        float xv = sX[tr * RPT + r][k];
        acc[r][0] = fmaf(xv, w.x, acc[r][0]);
        acc[r][1] = fmaf(xv, w.y, acc[r][1]);
        acc[r][2] = fmaf(xv, w.z, acc[r][2]);
        acc[r][3] = fmaf(xv, w.w, acc[r][3]);
      }
    }
    __syncthreads();
  }
  float4 bv = make_float4(0.f, 0.f, 0.f, 0.f);
  if (bias) bv = *(const float4*)(bias + tc * 4);
#pragma unroll
  for (int r = 0; r < RPT; ++r) {
    int grow = row0 + tr * RPT + r;
    if (grow < M) {
      float4 o;
      o.x = acc[r][0] + bv.x;
      o.y = acc[r][1] + bv.y;
      o.z = acc[r][2] + bv.z;
      o.w = acc[r][3] + bv.w;
      float4* yp = (float4*)(Y + (size_t)grow * NCOL + tc * 4);
      if (accumulate) {
        float4 p = *yp;
        o.x += p.x; o.y += p.y; o.z += p.z; o.w += p.w;
      }
      *yp = o;
    }
  }
}

// ---------------- mean aggregation: wave per node, gather-only ----------------

__global__ __launch_bounds__(256) void k_aggregate(const float* __restrict__ H, const int* __restrict__ rowptr,
                                                   const int* __restrict__ srclist, float* __restrict__ out, int n) {
  int w = (blockIdx.x * 256 + threadIdx.x) >> 6;
  int lane = threadIdx.x & 63;
  if (w >= n) return;
  int beg = rowptr[w], end = rowptr[w + 1];
  float ax = 0.f, ay = 0.f;
  for (int e = beg; e < end; ++e) {
    int s = srclist[e];
    float2 v = *(const float2*)(H + (size_t)s * 128 + lane * 2);
    ax += v.x;
    ay += v.y;
  }
  float inv = 1.f / fmaxf((float)(end - beg), 1.f);
  float2 o;
  o.x = ax * inv;
  o.y = ay * inv;
  *(float2*)(out + (size_t)w * 128 + lane * 2) = o;
}

// ---------------- LayerNorm(+optional residual)+ReLU: wave per row ----------------

__global__ __launch_bounds__(256) void k_ln_relu(const float* __restrict__ X, const float* __restrict__ R,
                                                 const float* __restrict__ gamma, const float* __restrict__ beta,
                                                 float* __restrict__ out, int n) {
  int w = (blockIdx.x * 256 + threadIdx.x) >> 6;
  int lane = threadIdx.x & 63;
  if (w >= n) return;
  float2 v = *(const float2*)(X + (size_t)w * 128 + lane * 2);
  if (R) {
    float2 rr = *(const float2*)(R + (size_t)w * 128 + lane * 2);
    v.x += rr.x;
    v.y += rr.y;
  }
  float sum = v.x + v.y;
#pragma unroll
  for (int off = 1; off < 64; off <<= 1) sum += __shfl_xor(sum, off, 64);
  float mu = sum * (1.f / 128.f);
  float dx = v.x - mu, dy = v.y - mu;
  float s2 = dx * dx + dy * dy;
#pragma unroll
  for (int off = 1; off < 64; off <<= 1) s2 += __shfl_xor(s2, off, 64);
  float scale = rsqrtf(s2 * (1.f / 128.f) + LN_EPS);
  float2 g = *(const float2*)(gamma + lane * 2);
  float2 b = *(const float2*)(beta + lane * 2);
  float2 o;
  o.x = fmaxf(dx * scale * g.x + b.x, 0.f);
  o.y = fmaxf(dy * scale * g.y + b.y, 0.f);
  *(float2*)(out + (size_t)w * 128 + lane * 2) = o;
}

// ---------------- launch ----------------

extern "C" void kernel_launch(void* const* d_in, const int* in_sizes, int n_in,
                              void* d_out, int out_size, void* d_ws, size_t ws_size,
                              hipStream_t stream) {
  const float* x = (const float*)d_in[0];
  const int* ei = (const int*)d_in[1];
  // d_in[2] = edge_attr: unused by the reference
  const float* W_ne = (const float*)d_in[3];
  const float* b_ne = (const float*)d_in[4];
  const float* W_l = (const float*)d_in[5];
  const float* b_l = (const float*)d_in[6];
  const float* W_r = (const float*)d_in[7];
  const float* gamma = (const float*)d_in[8];
  const float* beta = (const float*)d_in[9];
  const float* W_lin = (const float*)d_in[10];
  const float* b_lin = (const float*)d_in[11];
  float* out = (float*)d_out;

  const int N = in_sizes[0] / 128;
  const int E = in_sizes[1] / 2;

  char* ws = (char*)d_ws;
  const size_t S = (size_t)N * 128 * sizeof(float);
  float* A = (float*)(ws);           // h0, later h2-pre-residual
  float* B = (float*)(ws + S);       // mean, mean2, o
  float* C = (float*)(ws + 2 * S);   // h1
  float* D = (float*)(ws + 3 * S);   // r
  int* cnt = (int*)(ws + 4 * S);
  int* incl = cnt + N;
  int* rowptr = incl + N;            // N+1
  int* cursor = rowptr + (N + 1);
  int* bsums = cursor + N;           // up to 1024
  int* srclist = bsums + 1024;       // E

  const int nbS = (N + 255) / 256;       // scan blocks (196 <= 256, fits scan2)
  const int nbE = (E + 255) / 256;
  const int nbG = (N + 31) / 32;         // gemm row tiles
  const int nbW = ((N * 64) + 255) / 256;  // wave-per-node kernels

  hipMemsetAsync(cnt, 0, (size_t)N * sizeof(int), stream);
  hipMemsetAsync(cursor, 0, (size_t)N * sizeof(int), stream);
  k_hist<<<nbE, 256, 0, stream>>>(ei, cnt, E);
  k_scan1<<<nbS, 256, 0, stream>>>(cnt, incl, bsums, N);
  k_scan2<<<1, 256, 0, stream>>>(bsums, nbS);
  k_scan3<<<nbS, 256, 0, stream>>>(incl, bsums, rowptr, N);
  k_fill<<<nbE, 256, 0, stream>>>(ei, rowptr, cursor, srclist, E);

  k_gemm<128><<<nbG, 256, 0, stream>>>(x, W_ne, b_ne, A, N, 0);         // h0 = x@W_ne + b_ne
  k_aggregate<<<nbW, 256, 0, stream>>>(A, rowptr, srclist, B, N);       // mean(h0)
  k_gemm<128><<<nbG, 256, 0, stream>>>(B, W_l, b_l, C, N, 0);           // h1  = mean@W_l + b_l
  k_gemm<128><<<nbG, 256, 0, stream>>>(A, W_r, nullptr, C, N, 1);       // h1 += h0@W_r
  k_ln_relu<<<nbW, 256, 0, stream>>>(C, nullptr, gamma, beta, D, N);    // r = relu(LN(h1))
  k_aggregate<<<nbW, 256, 0, stream>>>(D, rowptr, srclist, B, N);       // mean(r)
  k_gemm<128><<<nbG, 256, 0, stream>>>(B, W_l, b_l, A, N, 0);           // t  = mean2@W_l + b_l
  k_gemm<128><<<nbG, 256, 0, stream>>>(D, W_r, nullptr, A, N, 1);       // t += r@W_r
  k_ln_relu<<<nbW, 256, 0, stream>>>(A, C, gamma, beta, B, N);          // o = relu(LN(t + h1))
  k_gemm<64><<<nbG, 256, 0, stream>>>(B, W_lin, b_lin, out, N, 0);      // out = o@W_lin + b_lin
}

// Round 2
// 390.832 us; speedup vs baseline: 1.2093x; 1.2093x over previous
//
#include <hip/hip_runtime.h>

constexpr float LN_EPS = 1e-5f;

// ---------------- CSR build ----------------

__global__ __launch_bounds__(256) void k_hist(const int* __restrict__ ei, int* __restrict__ cnt, int E) {
  int e = blockIdx.x * 256 + threadIdx.x;
  if (e < E) atomicAdd(&cnt[ei[E + e]], 1);
}

__global__ __launch_bounds__(256) void k_scan1(const int* __restrict__ in, int* __restrict__ out,
                                               int* __restrict__ bsums, int n) {
  __shared__ int s[256];
  int i = blockIdx.x * 256 + threadIdx.x;
  int v = (i < n) ? in[i] : 0;
  s[threadIdx.x] = v;
  __syncthreads();
  for (int off = 1; off < 256; off <<= 1) {
    int t = (threadIdx.x >= off) ? s[threadIdx.x - off] : 0;
    __syncthreads();
    s[threadIdx.x] += t;
    __syncthreads();
  }
  if (i < n) out[i] = s[threadIdx.x];
  if (threadIdx.x == 255) bsums[blockIdx.x] = s[255];
}

__global__ __launch_bounds__(256) void k_scan2(int* __restrict__ bsums, int nb) {
  __shared__ int s[256];
  int v = (threadIdx.x < nb) ? bsums[threadIdx.x] : 0;
  s[threadIdx.x] = v;
  __syncthreads();
  for (int off = 1; off < 256; off <<= 1) {
    int t = (threadIdx.x >= off) ? s[threadIdx.x - off] : 0;
    __syncthreads();
    s[threadIdx.x] += t;
    __syncthreads();
  }
  if (threadIdx.x < nb) bsums[threadIdx.x] = s[threadIdx.x] - v;  // exclusive
}

__global__ __launch_bounds__(256) void k_scan3(const int* __restrict__ incl, const int* __restrict__ bsums,
                                               int* __restrict__ rowptr, int n) {
  int i = blockIdx.x * 256 + threadIdx.x;
  if (i < n) rowptr[i + 1] = incl[i] + bsums[blockIdx.x];
  if (i == 0) rowptr[0] = 0;
}

__global__ __launch_bounds__(256) void k_fill(const int* __restrict__ ei, const int* __restrict__ rowptr,
                                              int* __restrict__ cursor, int* __restrict__ srclist, int E) {
  int e = blockIdx.x * 256 + threadIdx.x;
  if (e >= E) return;
  int s = ei[e];
  int d = ei[E + e];
  int pos = atomicAdd(&cursor[d], 1);
  srclist[rowptr[d] + pos] = s;
}

// ---------------- weight prep: WA=W_ne@W_l, WB=W_ne@W_r, bA=b_ne@W_l, bB=b_ne@W_r ----------------

__global__ __launch_bounds__(256) void k_prep(const float* __restrict__ W_ne, const float* __restrict__ b_ne,
                                              const float* __restrict__ W_l, const float* __restrict__ W_r,
                                              float* __restrict__ WA, float* __restrict__ WB,
                                              float* __restrict__ bA, float* __restrict__ bB) {
  __shared__ float srow[128];
  int j = threadIdx.x;
  const float* src = (blockIdx.x < 128) ? (W_ne + blockIdx.x * 128) : b_ne;
  if (j < 128) srow[j] = src[j];
  __syncthreads();
  int col = j & 127;
  const float* Wx = (j < 128) ? W_l : W_r;
  float acc = 0.f;
#pragma unroll 8
  for (int k = 0; k < 128; ++k) acc = fmaf(srow[k], Wx[k * 128 + col], acc);
  if (blockIdx.x < 128) {
    float* dst = (j < 128) ? WA : WB;
    dst[blockIdx.x * 128 + col] = acc;
  } else {
    float* dst = (j < 128) ? bA : bB;
    dst[col] = acc;
  }
}

// ---------------- fp32 GEMM: Y[M][NCOL] = X[M][128] @ W[128][NCOL] + bias ----------------
// 64 rows x NCOL cols per block, 256 threads, k-unrolled-by-4 float4 LDS reads.

template <int NCOL>
__global__ __launch_bounds__(256) void k_gemm(const float* __restrict__ X, const float* __restrict__ W,
                                              const float* __restrict__ bias, float* __restrict__ Y, int M) {
  constexpr int CT = NCOL / 4;      // threads along cols (each owns 4 cols)
  constexpr int RT = 256 / CT;      // thread-rows
  constexpr int RPT = 64 / RT;      // rows per thread
  __shared__ float4 sW4[64][CT];    // one 64-k chunk of W
  __shared__ float4 sX4[64][17];    // 64 rows x 16 float4 (+1 pad)
  const int tid = threadIdx.x;
  const int tc = tid % CT;
  const int tr = tid / CT;
  const int row0 = blockIdx.x * 64;
  const float4* X4 = (const float4*)X;
  const float4* W4 = (const float4*)W;

  float4 acc[RPT];
#pragma unroll
  for (int r = 0; r < RPT; ++r) acc[r] = make_float4(0.f, 0.f, 0.f, 0.f);

  for (int kc = 0; kc < 128; kc += 64) {
    // stage W chunk: rows kc..kc+63, all NCOL cols (contiguous float4s)
    constexpr int WV = 64 * CT;
    for (int i = tid; i < WV; i += 256) ((float4*)&sW4[0][0])[i] = W4[kc * CT + i];
    // stage X tile: 64 rows x 64 k (16 float4 per row)
    for (int i = tid; i < 64 * 16; i += 256) {
      int rr = i >> 4, cc = i & 15;
      int grow = row0 + rr;
      float4 v = make_float4(0.f, 0.f, 0.f, 0.f);
      if (grow < M) v = X4[(size_t)grow * 32 + (kc >> 2) + cc];
      sX4[rr][cc] = v;
    }
    __syncthreads();
#pragma unroll 4
    for (int kg = 0; kg < 16; ++kg) {
      float4 w0 = sW4[4 * kg + 0][tc];
      float4 w1 = sW4[4 * kg + 1][tc];
      float4 w2 = sW4[4 * kg + 2][tc];
      float4 w3 = sW4[4 * kg + 3][tc];
#pragma unroll
      for (int r = 0; r < RPT; ++r) {
        float4 xv = sX4[tr * RPT + r][kg];
        acc[r].x = fmaf(xv.x, w0.x, acc[r].x);
        acc[r].y = fmaf(xv.x, w0.y, acc[r].y);
        acc[r].z = fmaf(xv.x, w0.z, acc[r].z);
        acc[r].w = fmaf(xv.x, w0.w, acc[r].w);
        acc[r].x = fmaf(xv.y, w1.x, acc[r].x);
        acc[r].y = fmaf(xv.y, w1.y, acc[r].y);
        acc[r].z = fmaf(xv.y, w1.z, acc[r].z);
        acc[r].w = fmaf(xv.y, w1.w, acc[r].w);
        acc[r].x = fmaf(xv.z, w2.x, acc[r].x);
        acc[r].y = fmaf(xv.z, w2.y, acc[r].y);
        acc[r].z = fmaf(xv.z, w2.z, acc[r].z);
        acc[r].w = fmaf(xv.z, w2.w, acc[r].w);
        acc[r].x = fmaf(xv.w, w3.x, acc[r].x);
        acc[r].y = fmaf(xv.w, w3.y, acc[r].y);
        acc[r].z = fmaf(xv.w, w3.z, acc[r].z);
        acc[r].w = fmaf(xv.w, w3.w, acc[r].w);
      }
    }
    __syncthreads();
  }
  float4 bv = make_float4(0.f, 0.f, 0.f, 0.f);
  if (bias) bv = *(const float4*)(bias + tc * 4);
#pragma unroll
  for (int r = 0; r < RPT; ++r) {
    int grow = row0 + tr * RPT + r;
    if (grow < M) {
      float4 o = make_float4(acc[r].x + bv.x, acc[r].y + bv.y, acc[r].z + bv.z, acc[r].w + bv.w);
      ((float4*)Y)[(size_t)grow * CT + tc] = o;
    }
  }
}

// ---------------- LN+ReLU helper (wave holds full 128-wide row as float2/lane) ----------------

__device__ inline float2 ln_relu(float2 v, float2 g, float2 b) {
  float sum = v.x + v.y;
#pragma unroll
  for (int off = 1; off < 64; off <<= 1) sum += __shfl_xor(sum, off, 64);
  float mu = sum * (1.f / 128.f);
  float dx = v.x - mu, dy = v.y - mu;
  float s2 = dx * dx + dy * dy;
#pragma unroll
  for (int off = 1; off < 64; off <<= 1) s2 += __shfl_xor(s2, off, 64);
  float scale = rsqrtf(s2 * (1.f / 128.f) + LN_EPS);
  float2 o;
  o.x = fmaxf(dx * scale * g.x + b.x, 0.f);
  o.y = fmaxf(dy * scale * g.y + b.y, 0.f);
  return o;
}

// ---------------- fused aggregate 1: h1 = mean(p)+q+b_l ; r = relu(LN(h1)) ----------------

__global__ __launch_bounds__(256) void k_agg1(const float* __restrict__ P, const float* __restrict__ Q,
                                              const int* __restrict__ rowptr, const int* __restrict__ srclist,
                                              const float* __restrict__ b_l, const float* __restrict__ gamma,
                                              const float* __restrict__ beta, float* __restrict__ H1,
                                              float* __restrict__ R, int n) {
  int w = (blockIdx.x * 256 + threadIdx.x) >> 6;
  int lane = threadIdx.x & 63;
  if (w >= n) return;
  int beg = rowptr[w], end = rowptr[w + 1];
  float ax = 0.f, ay = 0.f;
  for (int base = beg; base < end; base += 64) {
    int m = end - base;
    if (m > 64) m = 64;
    int sidx = (lane < m) ? srclist[base + lane] : 0;
#pragma unroll 2
    for (int i = 0; i < m; ++i) {
      int s = __shfl(sidx, i, 64);
      float2 v = *(const float2*)(P + (size_t)s * 128 + lane * 2);
      ax += v.x;
      ay += v.y;
    }
  }
  float inv = 1.f / fmaxf((float)(end - beg), 1.f);
  float2 q = *(const float2*)(Q + (size_t)w * 128 + lane * 2);
  float2 bl = *(const float2*)(b_l + lane * 2);
  float2 h;
  h.x = ax * inv + q.x + bl.x;
  h.y = ay * inv + q.y + bl.y;
  *(float2*)(H1 + (size_t)w * 128 + lane * 2) = h;
  float2 g = *(const float2*)(gamma + lane * 2);
  float2 b = *(const float2*)(beta + lane * 2);
  float2 r = ln_relu(h, g, b);
  *(float2*)(R + (size_t)w * 128 + lane * 2) = r;
}

// ---------------- fused aggregate 2: o = relu(LN(mean(u)+v+b_l + h1)) ----------------

__global__ __launch_bounds__(256) void k_agg2(const float* __restrict__ U, const float* __restrict__ V,
                                              const float* __restrict__ H1, const int* __restrict__ rowptr,
                                              const int* __restrict__ srclist, const float* __restrict__ b_l,
                                              const float* __restrict__ gamma, const float* __restrict__ beta,
                                              float* __restrict__ O, int n) {
  int w = (blockIdx.x * 256 + threadIdx.x) >> 6;
  int lane = threadIdx.x & 63;
  if (w >= n) return;
  int beg = rowptr[w], end = rowptr[w + 1];
  float ax = 0.f, ay = 0.f;
  for (int base = beg; base < end; base += 64) {
    int m = end - base;
    if (m > 64) m = 64;
    int sidx = (lane < m) ? srclist[base + lane] : 0;
#pragma unroll 2
    for (int i = 0; i < m; ++i) {
      int s = __shfl(sidx, i, 64);
      float2 v = *(const float2*)(U + (size_t)s * 128 + lane * 2);
      ax += v.x;
      ay += v.y;
    }
  }
  float inv = 1.f / fmaxf((float)(end - beg), 1.f);
  float2 v = *(const float2*)(V + (size_t)w * 128 + lane * 2);
  float2 bl = *(const float2*)(b_l + lane * 2);
  float2 h1 = *(const float2*)(H1 + (size_t)w * 128 + lane * 2);
  float2 h;
  h.x = ax * inv + v.x + bl.x + h1.x;
  h.y = ay * inv + v.y + bl.y + h1.y;
  float2 g = *(const float2*)(gamma + lane * 2);
  float2 b = *(const float2*)(beta + lane * 2);
  float2 o = ln_relu(h, g, b);
  *(float2*)(O + (size_t)w * 128 + lane * 2) = o;
}

// ---------------- launch ----------------

extern "C" void kernel_launch(void* const* d_in, const int* in_sizes, int n_in,
                              void* d_out, int out_size, void* d_ws, size_t ws_size,
                              hipStream_t stream) {
  const float* x = (const float*)d_in[0];
  const int* ei = (const int*)d_in[1];
  // d_in[2] = edge_attr: unused by the reference
  const float* W_ne = (const float*)d_in[3];
  const float* b_ne = (const float*)d_in[4];
  const float* W_l = (const float*)d_in[5];
  const float* b_l = (const float*)d_in[6];
  const float* W_r = (const float*)d_in[7];
  const float* gamma = (const float*)d_in[8];
  const float* beta = (const float*)d_in[9];
  const float* W_lin = (const float*)d_in[10];
  const float* b_lin = (const float*)d_in[11];
  float* out = (float*)d_out;

  const int N = in_sizes[0] / 128;
  const int E = in_sizes[1] / 2;

  char* ws = (char*)d_ws;
  const size_t S = (size_t)N * 128 * sizeof(float);
  float* A = (float*)(ws);           // Pp, later U
  float* B = (float*)(ws + S);       // Pq, later V
  float* C = (float*)(ws + 2 * S);   // h1
  float* D = (float*)(ws + 3 * S);   // r, later o
  char* p = ws + 4 * S;
  int* cnt = (int*)p;                p += (size_t)N * sizeof(int);
  int* incl = (int*)p;               p += (size_t)N * sizeof(int);
  int* rowptr = (int*)p;             p += (size_t)(N + 1) * sizeof(int);
  int* cursor = (int*)p;             p += (size_t)N * sizeof(int);
  int* bsums = (int*)p;              p += 1024 * sizeof(int);
  int* srclist = (int*)p;            p += (size_t)E * sizeof(int);
  float* WA = (float*)p;             p += 128 * 128 * sizeof(float);
  float* WB = (float*)p;             p += 128 * 128 * sizeof(float);
  float* bA = (float*)p;             p += 128 * sizeof(float);
  float* bB = (float*)p;             p += 128 * sizeof(float);

  const int nbS = (N + 255) / 256;
  const int nbE = (E + 255) / 256;
  const int nbG = (N + 63) / 64;
  const int nbW = ((N * 64) + 255) / 256;

  hipMemsetAsync(cnt, 0, (size_t)N * sizeof(int), stream);
  hipMemsetAsync(cursor, 0, (size_t)N * sizeof(int), stream);
  k_hist<<<nbE, 256, 0, stream>>>(ei, cnt, E);
  k_scan1<<<nbS, 256, 0, stream>>>(cnt, incl, bsums, N);
  k_scan2<<<1, 256, 0, stream>>>(bsums, nbS);
  k_scan3<<<nbS, 256, 0, stream>>>(incl, bsums, rowptr, N);
  k_fill<<<nbE, 256, 0, stream>>>(ei, rowptr, cursor, srclist, E);
  k_prep<<<129, 256, 0, stream>>>(W_ne, b_ne, W_l, W_r, WA, WB, bA, bB);

  k_gemm<128><<<nbG, 256, 0, stream>>>(x, WA, bA, A, N);                 // Pp = x@WA + bA
  k_gemm<128><<<nbG, 256, 0, stream>>>(x, WB, bB, B, N);                 // Pq = x@WB + bB
  k_agg1<<<nbW, 256, 0, stream>>>(A, B, rowptr, srclist, b_l, gamma, beta, C, D, N);
  k_gemm<128><<<nbG, 256, 0, stream>>>(D, W_l, nullptr, A, N);           // U = r@W_l
  k_gemm<128><<<nbG, 256, 0, stream>>>(D, W_r, nullptr, B, N);           // V = r@W_r
  k_agg2<<<nbW, 256, 0, stream>>>(A, B, C, rowptr, srclist, b_l, gamma, beta, D, N);
  k_gemm<64><<<nbG, 256, 0, stream>>>(D, W_lin, b_lin, out, N);          // out = o@W_lin + b_lin
}

// Round 3
// 304.757 us; speedup vs baseline: 1.5508x; 1.2824x over previous
//
#include <hip/hip_runtime.h>

typedef __attribute__((ext_vector_type(8))) short bf16x8;
typedef __attribute__((ext_vector_type(4))) float f32x4;

constexpr float LN_EPS = 1e-5f;

__device__ inline ushort f2bf(float f) {
  uint u = __float_as_uint(f);
  u += 0x7FFF + ((u >> 16) & 1);   // round-to-nearest-even
  return (ushort)(u >> 16);
}
__device__ inline float bflo(uint u) { return __uint_as_float(u << 16); }
__device__ inline float bfhi(uint u) { return __uint_as_float(u & 0xFFFF0000u); }

// ---------------- CSR build ----------------

__global__ __launch_bounds__(256) void k_hist(const int* __restrict__ ei, int* __restrict__ cnt, int E) {
  int e = blockIdx.x * 256 + threadIdx.x;
  if (e < E) atomicAdd(&cnt[ei[E + e]], 1);
}

__global__ __launch_bounds__(256) void k_scan1(const int* __restrict__ in, int* __restrict__ out,
                                               int* __restrict__ bsums, int n) {
  __shared__ int s[256];
  int i = blockIdx.x * 256 + threadIdx.x;
  int v = (i < n) ? in[i] : 0;
  s[threadIdx.x] = v;
  __syncthreads();
  for (int off = 1; off < 256; off <<= 1) {
    int t = (threadIdx.x >= off) ? s[threadIdx.x - off] : 0;
    __syncthreads();
    s[threadIdx.x] += t;
    __syncthreads();
  }
  if (i < n) out[i] = s[threadIdx.x];
  if (threadIdx.x == 255) bsums[blockIdx.x] = s[255];
}

__global__ __launch_bounds__(256) void k_scan2(int* __restrict__ bsums, int nb) {
  __shared__ int s[256];
  int v = (threadIdx.x < nb) ? bsums[threadIdx.x] : 0;
  s[threadIdx.x] = v;
  __syncthreads();
  for (int off = 1; off < 256; off <<= 1) {
    int t = (threadIdx.x >= off) ? s[threadIdx.x - off] : 0;
    __syncthreads();
    s[threadIdx.x] += t;
    __syncthreads();
  }
  if (threadIdx.x < nb) bsums[threadIdx.x] = s[threadIdx.x] - v;  // exclusive
}

__global__ __launch_bounds__(256) void k_scan3(const int* __restrict__ incl, const int* __restrict__ bsums,
                                               int* __restrict__ rowptr, int n) {
  int i = blockIdx.x * 256 + threadIdx.x;
  if (i < n) rowptr[i + 1] = incl[i] + bsums[blockIdx.x];
  if (i == 0) rowptr[0] = 0;
}

__global__ __launch_bounds__(256) void k_fill(const int* __restrict__ ei, const int* __restrict__ rowptr,
                                              int* __restrict__ cursor, int* __restrict__ srclist, int E) {
  int e = blockIdx.x * 256 + threadIdx.x;
  if (e >= E) return;
  int s = ei[e];
  int d = ei[E + e];
  int pos = atomicAdd(&cursor[d], 1);
  srclist[rowptr[d] + pos] = s;
}

// ---------------- weight prep ----------------
// blocks 0..127: row i of WA=W_ne@W_l / WB=W_ne@W_r -> bf16 transposed [col][k]
// block 128: bA=b_ne@W_l, bB=b_ne@W_r (fp32)

__global__ __launch_bounds__(256) void k_prep(const float* __restrict__ W_ne, const float* __restrict__ b_ne,
                                              const float* __restrict__ W_l, const float* __restrict__ W_r,
                                              ushort* __restrict__ WAt, ushort* __restrict__ WBt,
                                              float* __restrict__ bA, float* __restrict__ bB) {
  __shared__ float srow[128];
  int j = threadIdx.x;
  const float* src = (blockIdx.x < 128) ? (W_ne + blockIdx.x * 128) : b_ne;
  if (j < 128) srow[j] = src[j];
  __syncthreads();
  int col = j & 127;
  const float* Wx = (j < 128) ? W_l : W_r;
  float acc = 0.f;
#pragma unroll 8
  for (int k = 0; k < 128; ++k) acc = fmaf(srow[k], Wx[k * 128 + col], acc);
  if (blockIdx.x < 128) {
    ushort* dst = (j < 128) ? WAt : WBt;
    dst[col * 128 + blockIdx.x] = f2bf(acc);
  } else {
    float* dst = (j < 128) ? bA : bB;
    dst[col] = acc;
  }
}

// transpose+cast: W [128][C] fp32 -> Wt [C][128] bf16
template <int C>
__global__ __launch_bounds__(256) void k_tcast(const float* __restrict__ W, ushort* __restrict__ Wt) {
  int idx = blockIdx.x * 256 + threadIdx.x;
  if (idx < 128 * C) {
    int k = idx / C, c = idx % C;
    Wt[c * 128 + k] = f2bf(W[idx]);
  }
}

// ---------------- MFMA GEMM: Y[M][NCOL] = X[M][128] @ W[128][NCOL] (+bias) ----------------
// Wt is bf16 W^T [NCOL][128]. TIN: float (cast on stage) or ushort (bf16).
// Block: 128 rows x NCOL cols, 4 waves in 2x2, K=128 single stage.

template <int NCOL, typename TIN, typename TOUT>
__global__ __launch_bounds__(256) void k_gemm(const TIN* __restrict__ X, const ushort* __restrict__ Wt,
                                              const float* __restrict__ bias, TOUT* __restrict__ Y, int M) {
  constexpr int LD = 136;          // bf16 elems per LDS row (272B: bank-balanced b128 reads)
  constexpr int NF = NCOL / 32;    // 16-wide n-frags per wave (wave covers NCOL/2 cols)
  __shared__ ushort sX[128 * LD];
  __shared__ ushort sW[NCOL * LD];
  const int tid = threadIdx.x;
  const int row0 = blockIdx.x * 128;

  for (int i = tid; i < NCOL * 16; i += 256) {
    int r = i >> 4, c8 = i & 15;
    *(uint4*)&sW[r * LD + c8 * 8] = *(const uint4*)(Wt + r * 128 + c8 * 8);
  }
  for (int i = tid; i < 128 * 16; i += 256) {
    int r = i >> 4, c8 = i & 15;
    int grow = row0 + r;
    uint4 v;
    if constexpr (sizeof(TIN) == 4) {
      float4 a = make_float4(0.f, 0.f, 0.f, 0.f), b = a;
      if (grow < M) {
        const float* Xf = (const float*)X + (size_t)grow * 128 + c8 * 8;
        a = *(const float4*)Xf;
        b = *(const float4*)(Xf + 4);
      }
      v.x = (uint)f2bf(a.x) | ((uint)f2bf(a.y) << 16);
      v.y = (uint)f2bf(a.z) | ((uint)f2bf(a.w) << 16);
      v.z = (uint)f2bf(b.x) | ((uint)f2bf(b.y) << 16);
      v.w = (uint)f2bf(b.z) | ((uint)f2bf(b.w) << 16);
    } else {
      v.x = v.y = v.z = v.w = 0u;
      if (grow < M) v = *(const uint4*)((const ushort*)X + (size_t)grow * 128 + c8 * 8);
    }
    *(uint4*)&sX[r * LD + c8 * 8] = v;
  }
  __syncthreads();

  const int wave = tid >> 6;
  const int lane = tid & 63;
  const int rbase = (wave >> 1) * 64;
  const int cbase = (wave & 1) * (NCOL / 2);
  const int lrow = lane & 15;
  const int lk = (lane >> 4) * 8;

  f32x4 acc[4][NF];
#pragma unroll
  for (int mf = 0; mf < 4; ++mf)
#pragma unroll
    for (int nf = 0; nf < NF; ++nf) acc[mf][nf] = (f32x4){0.f, 0.f, 0.f, 0.f};

#pragma unroll
  for (int ks = 0; ks < 4; ++ks) {
    bf16x8 a[4], b[NF];
#pragma unroll
    for (int mf = 0; mf < 4; ++mf)
      a[mf] = *(const bf16x8*)&sX[(rbase + mf * 16 + lrow) * LD + ks * 32 + lk];
#pragma unroll
    for (int nf = 0; nf < NF; ++nf)
      b[nf] = *(const bf16x8*)&sW[(cbase + nf * 16 + lrow) * LD + ks * 32 + lk];
#pragma unroll
    for (int mf = 0; mf < 4; ++mf)
#pragma unroll
      for (int nf = 0; nf < NF; ++nf)
        acc[mf][nf] = __builtin_amdgcn_mfma_f32_16x16x32_bf16(a[mf], b[nf], acc[mf][nf], 0, 0, 0);
  }

#pragma unroll
  for (int nf = 0; nf < NF; ++nf) {
    int col = cbase + nf * 16 + lrow;
    float bv = bias ? bias[col] : 0.f;
#pragma unroll
    for (int mf = 0; mf < 4; ++mf) {
#pragma unroll
      for (int r = 0; r < 4; ++r) {
        int grow = row0 + rbase + mf * 16 + (lane >> 4) * 4 + r;
        if (grow < M) {
          float val = acc[mf][nf][r] + bv;
          if constexpr (sizeof(TOUT) == 4)
            ((float*)Y)[(size_t)grow * NCOL + col] = val;
          else
            ((ushort*)Y)[(size_t)grow * NCOL + col] = f2bf(val);
        }
      }
    }
  }
}

// ---------------- LN+ReLU helper ----------------

__device__ inline float2 ln_relu(float2 v, float2 g, float2 b) {
  float sum = v.x + v.y;
#pragma unroll
  for (int off = 1; off < 64; off <<= 1) sum += __shfl_xor(sum, off, 64);
  float mu = sum * (1.f / 128.f);
  float dx = v.x - mu, dy = v.y - mu;
  float s2 = dx * dx + dy * dy;
#pragma unroll
  for (int off = 1; off < 64; off <<= 1) s2 += __shfl_xor(s2, off, 64);
  float scale = rsqrtf(s2 * (1.f / 128.f) + LN_EPS);
  float2 o;
  o.x = fmaxf(dx * scale * g.x + b.x, 0.f);
  o.y = fmaxf(dy * scale * g.y + b.y, 0.f);
  return o;
}

// ---------------- agg1: h1 = mean(P)+Q+b_l (fp32 out) ; r = relu(LN(h1)) (bf16 out) ----------------

__global__ __launch_bounds__(256) void k_agg1(const ushort* __restrict__ P, const float* __restrict__ Q,
                                              const int* __restrict__ rowptr, const int* __restrict__ srclist,
                                              const float* __restrict__ b_l, const float* __restrict__ gamma,
                                              const float* __restrict__ beta, float* __restrict__ H1,
                                              ushort* __restrict__ R, int n) {
  int w = (blockIdx.x * 256 + threadIdx.x) >> 6;
  int lane = threadIdx.x & 63;
  if (w >= n) return;
  const uint* P2 = (const uint*)P;
  int beg = rowptr[w], end = rowptr[w + 1];
  float ax = 0.f, ay = 0.f;
  for (int base = beg; base < end; base += 64) {
    int m = end - base;
    if (m > 64) m = 64;
    int sidx = (lane < m) ? srclist[base + lane] : 0;
#pragma unroll 2
    for (int i = 0; i < m; ++i) {
      int s = __shfl(sidx, i, 64);
      uint u = P2[(size_t)s * 64 + lane];
      ax += bflo(u);
      ay += bfhi(u);
    }
  }
  float inv = 1.f / fmaxf((float)(end - beg), 1.f);
  float2 q = *(const float2*)(Q + (size_t)w * 128 + lane * 2);
  float2 bl = *(const float2*)(b_l + lane * 2);
  float2 h;
  h.x = ax * inv + q.x + bl.x;
  h.y = ay * inv + q.y + bl.y;
  *(float2*)(H1 + (size_t)w * 128 + lane * 2) = h;
  float2 g = *(const float2*)(gamma + lane * 2);
  float2 b = *(const float2*)(beta + lane * 2);
  float2 r = ln_relu(h, g, b);
  ((uint*)R)[(size_t)w * 64 + lane] = (uint)f2bf(r.x) | ((uint)f2bf(r.y) << 16);
}

// ---------------- agg2: o = relu(LN(mean(U)+V+b_l+h1)) (bf16 out) ----------------

__global__ __launch_bounds__(256) void k_agg2(const ushort* __restrict__ U, const float* __restrict__ V,
                                              const float* __restrict__ H1, const int* __restrict__ rowptr,
                                              const int* __restrict__ srclist, const float* __restrict__ b_l,
                                              const float* __restrict__ gamma, const float* __restrict__ beta,
                                              ushort* __restrict__ O, int n) {
  int w = (blockIdx.x * 256 + threadIdx.x) >> 6;
  int lane = threadIdx.x & 63;
  if (w >= n) return;
  const uint* U2 = (const uint*)U;
  int beg = rowptr[w], end = rowptr[w + 1];
  float ax = 0.f, ay = 0.f;
  for (int base = beg; base < end; base += 64) {
    int m = end - base;
    if (m > 64) m = 64;
    int sidx = (lane < m) ? srclist[base + lane] : 0;
#pragma unroll 2
    for (int i = 0; i < m; ++i) {
      int s = __shfl(sidx, i, 64);
      uint u = U2[(size_t)s * 64 + lane];
      ax += bflo(u);
      ay += bfhi(u);
    }
  }
  float inv = 1.f / fmaxf((float)(end - beg), 1.f);
  float2 v = *(const float2*)(V + (size_t)w * 128 + lane * 2);
  float2 bl = *(const float2*)(b_l + lane * 2);
  float2 h1 = *(const float2*)(H1 + (size_t)w * 128 + lane * 2);
  float2 h;
  h.x = ax * inv + v.x + bl.x + h1.x;
  h.y = ay * inv + v.y + bl.y + h1.y;
  float2 g = *(const float2*)(gamma + lane * 2);
  float2 b = *(const float2*)(beta + lane * 2);
  float2 o = ln_relu(h, g, b);
  ((uint*)O)[(size_t)w * 64 + lane] = (uint)f2bf(o.x) | ((uint)f2bf(o.y) << 16);
}

// ---------------- launch ----------------

extern "C" void kernel_launch(void* const* d_in, const int* in_sizes, int n_in,
                              void* d_out, int out_size, void* d_ws, size_t ws_size,
                              hipStream_t stream) {
  const float* x = (const float*)d_in[0];
  const int* ei = (const int*)d_in[1];
  // d_in[2] = edge_attr: unused by the reference
  const float* W_ne = (const float*)d_in[3];
  const float* b_ne = (const float*)d_in[4];
  const float* W_l = (const float*)d_in[5];
  const float* b_l = (const float*)d_in[6];
  const float* W_r = (const float*)d_in[7];
  const float* gamma = (const float*)d_in[8];
  const float* beta = (const float*)d_in[9];
  const float* W_lin = (const float*)d_in[10];
  const float* b_lin = (const float*)d_in[11];
  float* out = (float*)d_out;

  const int N = in_sizes[0] / 128;
  const int E = in_sizes[1] / 2;

  char* p = (char*)d_ws;
  const size_t S2 = (size_t)N * 128 * sizeof(ushort);
  const size_t S4 = (size_t)N * 128 * sizeof(float);
  ushort* Abf = (ushort*)p;      p += S2;   // Pp bf16, later U bf16
  float* Bf = (float*)p;         p += S4;   // Pq fp32, later V fp32
  float* Cf = (float*)p;         p += S4;   // h1 fp32
  ushort* Dbf = (ushort*)p;      p += S2;   // r bf16, later o bf16
  ushort* WAt = (ushort*)p;      p += 128 * 128 * sizeof(ushort);
  ushort* WBt = (ushort*)p;      p += 128 * 128 * sizeof(ushort);
  ushort* Wlt = (ushort*)p;      p += 128 * 128 * sizeof(ushort);
  ushort* Wrt = (ushort*)p;      p += 128 * 128 * sizeof(ushort);
  ushort* Wlint = (ushort*)p;    p += 64 * 128 * sizeof(ushort);
  float* bA = (float*)p;         p += 128 * sizeof(float);
  float* bB = (float*)p;         p += 128 * sizeof(float);
  int* cnt = (int*)p;            p += (size_t)N * sizeof(int);
  int* incl = (int*)p;           p += (size_t)N * sizeof(int);
  int* rowptr = (int*)p;         p += ((size_t)N + 4) * sizeof(int);
  int* cursor = (int*)p;         p += (size_t)N * sizeof(int);
  int* bsums = (int*)p;          p += 1024 * sizeof(int);
  int* srclist = (int*)p;

  const int nbS = (N + 255) / 256;
  const int nbE = (E + 255) / 256;
  const int nbG = (N + 127) / 128;
  const int nbW = ((N * 64) + 255) / 256;

  hipMemsetAsync(cnt, 0, (size_t)N * sizeof(int), stream);
  hipMemsetAsync(cursor, 0, (size_t)N * sizeof(int), stream);
  k_hist<<<nbE, 256, 0, stream>>>(ei, cnt, E);
  k_scan1<<<nbS, 256, 0, stream>>>(cnt, incl, bsums, N);
  k_scan2<<<1, 256, 0, stream>>>(bsums, nbS);
  k_scan3<<<nbS, 256, 0, stream>>>(incl, bsums, rowptr, N);
  k_fill<<<nbE, 256, 0, stream>>>(ei, rowptr, cursor, srclist, E);
  k_prep<<<129, 256, 0, stream>>>(W_ne, b_ne, W_l, W_r, WAt, WBt, bA, bB);
  k_tcast<128><<<64, 256, 0, stream>>>(W_l, Wlt);
  k_tcast<128><<<64, 256, 0, stream>>>(W_r, Wrt);
  k_tcast<64><<<32, 256, 0, stream>>>(W_lin, Wlint);

  k_gemm<128, float, ushort><<<nbG, 256, 0, stream>>>(x, WAt, bA, Abf, N);   // Pp = x@WA+bA (bf16)
  k_gemm<128, float, float><<<nbG, 256, 0, stream>>>(x, WBt, bB, Bf, N);     // Pq = x@WB+bB (fp32)
  k_agg1<<<nbW, 256, 0, stream>>>(Abf, Bf, rowptr, srclist, b_l, gamma, beta, Cf, Dbf, N);
  k_gemm<128, ushort, ushort><<<nbG, 256, 0, stream>>>(Dbf, Wlt, nullptr, Abf, N);  // U = r@W_l (bf16)
  k_gemm<128, ushort, float><<<nbG, 256, 0, stream>>>(Dbf, Wrt, nullptr, Bf, N);    // V = r@W_r (fp32)
  k_agg2<<<nbW, 256, 0, stream>>>(Abf, Bf, Cf, rowptr, srclist, b_l, gamma, beta, Dbf, N);
  k_gemm<64, ushort, float><<<nbG, 256, 0, stream>>>(Dbf, Wlint, b_lin, out, N);    // out = o@W_lin+b_lin
}

// Round 4
// 270.224 us; speedup vs baseline: 1.7490x; 1.1278x over previous
//
#include <hip/hip_runtime.h>

typedef __attribute__((ext_vector_type(8))) short bf16x8;
typedef __attribute__((ext_vector_type(4))) float f32x4;

constexpr float LN_EPS = 1e-5f;

__device__ inline ushort f2bf(float f) {
  uint u = __float_as_uint(f);
  u += 0x7FFF + ((u >> 16) & 1);   // round-to-nearest-even
  return (ushort)(u >> 16);
}
__device__ inline float bflo(uint u) { return __uint_as_float(u << 16); }
__device__ inline float bfhi(uint u) { return __uint_as_float(u & 0xFFFF0000u); }

// ---------------- CSR build ----------------

__global__ __launch_bounds__(256) void k_hist(const int* __restrict__ ei, int* __restrict__ cnt, int E) {
  int e = blockIdx.x * 256 + threadIdx.x;
  if (e < E) atomicAdd(&cnt[ei[E + e]], 1);
}

__global__ __launch_bounds__(256) void k_scan1(const int* __restrict__ in, int* __restrict__ out,
                                               int* __restrict__ bsums, int n) {
  __shared__ int s[256];
  int i = blockIdx.x * 256 + threadIdx.x;
  int v = (i < n) ? in[i] : 0;
  s[threadIdx.x] = v;
  __syncthreads();
  for (int off = 1; off < 256; off <<= 1) {
    int t = (threadIdx.x >= off) ? s[threadIdx.x - off] : 0;
    __syncthreads();
    s[threadIdx.x] += t;
    __syncthreads();
  }
  if (i < n) out[i] = s[threadIdx.x];
  if (threadIdx.x == 255) bsums[blockIdx.x] = s[255];
}

__global__ __launch_bounds__(256) void k_scan2(int* __restrict__ bsums, int nb) {
  __shared__ int s[256];
  int v = (threadIdx.x < nb) ? bsums[threadIdx.x] : 0;
  s[threadIdx.x] = v;
  __syncthreads();
  for (int off = 1; off < 256; off <<= 1) {
    int t = (threadIdx.x >= off) ? s[threadIdx.x - off] : 0;
    __syncthreads();
    s[threadIdx.x] += t;
    __syncthreads();
  }
  if (threadIdx.x < nb) bsums[threadIdx.x] = s[threadIdx.x] - v;  // exclusive
}

// writes rowptr AND cursor (= row start) so k_fill needs no rowptr lookup and no cursor memset
__global__ __launch_bounds__(256) void k_scan3(const int* __restrict__ incl, const int* __restrict__ bsums,
                                               const int* __restrict__ cnt, int* __restrict__ rowptr,
                                               int* __restrict__ cursor, int n) {
  int i = blockIdx.x * 256 + threadIdx.x;
  if (i < n) {
    int inc = incl[i] + bsums[blockIdx.x];
    rowptr[i + 1] = inc;
    cursor[i] = inc - cnt[i];
  }
  if (i == 0) rowptr[0] = 0;
}

__global__ __launch_bounds__(256) void k_fill(const int* __restrict__ ei, int* __restrict__ cursor,
                                              int* __restrict__ srclist, int E) {
  int e = blockIdx.x * 256 + threadIdx.x;
  if (e >= E) return;
  int s = ei[e];
  int d = ei[E + e];
  int pos = atomicAdd(&cursor[d], 1);
  srclist[pos] = s;
}

// ---------------- weight prep ----------------
// blocks 0..127: row i of WA=W_ne@W_l / WB=W_ne@W_r -> bf16 transposed [col][k]
// block 128: bA=b_ne@W_l, bB=b_ne@W_r (fp32)

__global__ __launch_bounds__(256) void k_prep(const float* __restrict__ W_ne, const float* __restrict__ b_ne,
                                              const float* __restrict__ W_l, const float* __restrict__ W_r,
                                              ushort* __restrict__ WAt, ushort* __restrict__ WBt,
                                              float* __restrict__ bA, float* __restrict__ bB) {
  __shared__ float srow[128];
  int j = threadIdx.x;
  const float* src = (blockIdx.x < 128) ? (W_ne + blockIdx.x * 128) : b_ne;
  if (j < 128) srow[j] = src[j];
  __syncthreads();
  int col = j & 127;
  const float* Wx = (j < 128) ? W_l : W_r;
  float acc = 0.f;
#pragma unroll 8
  for (int k = 0; k < 128; ++k) acc = fmaf(srow[k], Wx[k * 128 + col], acc);
  if (blockIdx.x < 128) {
    ushort* dst = (j < 128) ? WAt : WBt;
    dst[col * 128 + blockIdx.x] = f2bf(acc);
  } else {
    float* dst = (j < 128) ? bA : bB;
    dst[col] = acc;
  }
}

// ---------------- all casts in one dispatch ----------------
// x [N][128] f32 -> xbf bf16 (8/thread); W_l,W_r [128][128] -> transposed bf16; W_lin [128][64] -> [64][128] bf16

__global__ __launch_bounds__(256) void k_cast_all(const float* __restrict__ x, const float* __restrict__ W_l,
                                                  const float* __restrict__ W_r, const float* __restrict__ W_lin,
                                                  ushort* __restrict__ xbf, ushort* __restrict__ Wlt,
                                                  ushort* __restrict__ Wrt, ushort* __restrict__ Wlint, int N) {
  int nx8 = N * 16;
  int idx = blockIdx.x * 256 + threadIdx.x;
  if (idx < nx8) {
    const float4* xin = (const float4*)x;
    float4 a = xin[2 * (size_t)idx];
    float4 b = xin[2 * (size_t)idx + 1];
    uint4 v;
    v.x = (uint)f2bf(a.x) | ((uint)f2bf(a.y) << 16);
    v.y = (uint)f2bf(a.z) | ((uint)f2bf(a.w) << 16);
    v.z = (uint)f2bf(b.x) | ((uint)f2bf(b.y) << 16);
    v.w = (uint)f2bf(b.z) | ((uint)f2bf(b.w) << 16);
    ((uint4*)xbf)[idx] = v;
    return;
  }
  int t = idx - nx8;
  if (t < 16384) { Wlt[(t & 127) * 128 + (t >> 7)] = f2bf(W_l[t]); return; }
  t -= 16384;
  if (t < 16384) { Wrt[(t & 127) * 128 + (t >> 7)] = f2bf(W_r[t]); return; }
  t -= 16384;
  if (t < 8192) { Wlint[(t & 63) * 128 + (t >> 6)] = f2bf(W_lin[t]); return; }
}

// ---------------- no-LDS MFMA GEMM: Y[M][NCOL] = X[M][128] @ Wt^T (+bias) ----------------
// X bf16 row-major [M][128]; Wt bf16 [NCOL][128]. blockIdx.y picks (Wt,bias,Y).
// Block: 128 rows x NCOL cols, 4 waves 2x2. Fragments loaded direct from global (L2-resident).

template <int NCOL, typename TOUT>
__global__ __launch_bounds__(256) void k_gemm(const ushort* __restrict__ X,
                                              const ushort* __restrict__ Wt0, const ushort* __restrict__ Wt1,
                                              const float* __restrict__ bias0, const float* __restrict__ bias1,
                                              TOUT* __restrict__ Y0, TOUT* __restrict__ Y1, int M) {
  const ushort* Wt = blockIdx.y ? Wt1 : Wt0;
  const float* bias = blockIdx.y ? bias1 : bias0;
  TOUT* Y = blockIdx.y ? Y1 : Y0;
  constexpr int NF = NCOL / 32;
  const int tid = threadIdx.x;
  const int wave = tid >> 6, lane = tid & 63;
  const int rbase = (wave >> 1) * 64;
  const int cbase = (wave & 1) * (NCOL / 2);
  const int lrow = lane & 15;
  const int lkb = (lane >> 4) * 8;
  const int row0 = blockIdx.x * 128;

  size_t rIdx[4];
#pragma unroll
  for (int mf = 0; mf < 4; ++mf) {
    int r = row0 + rbase + mf * 16 + lrow;
    rIdx[mf] = (size_t)((r < M) ? r : (M - 1));
  }

  f32x4 acc[4][NF];
#pragma unroll
  for (int mf = 0; mf < 4; ++mf)
#pragma unroll
    for (int nf = 0; nf < NF; ++nf) acc[mf][nf] = (f32x4){0.f, 0.f, 0.f, 0.f};

#pragma unroll
  for (int ks = 0; ks < 4; ++ks) {
    bf16x8 a[4], b[NF];
#pragma unroll
    for (int mf = 0; mf < 4; ++mf)
      a[mf] = *(const bf16x8*)(X + rIdx[mf] * 128 + ks * 32 + lkb);
#pragma unroll
    for (int nf = 0; nf < NF; ++nf)
      b[nf] = *(const bf16x8*)(Wt + (size_t)(cbase + nf * 16 + lrow) * 128 + ks * 32 + lkb);
#pragma unroll
    for (int mf = 0; mf < 4; ++mf)
#pragma unroll
      for (int nf = 0; nf < NF; ++nf)
        acc[mf][nf] = __builtin_amdgcn_mfma_f32_16x16x32_bf16(a[mf], b[nf], acc[mf][nf], 0, 0, 0);
  }

#pragma unroll
  for (int nf = 0; nf < NF; ++nf) {
    int col = cbase + nf * 16 + lrow;
    float bv = bias ? bias[col] : 0.f;
#pragma unroll
    for (int mf = 0; mf < 4; ++mf) {
      int growb = row0 + rbase + mf * 16 + (lane >> 4) * 4;
#pragma unroll
      for (int r = 0; r < 4; ++r) {
        int grow = growb + r;
        if (grow < M) {
          float val = acc[mf][nf][r] + bv;
          if constexpr (sizeof(TOUT) == 4)
            Y[(size_t)grow * NCOL + col] = val;
          else
            Y[(size_t)grow * NCOL + col] = (TOUT)f2bf(val);
        }
      }
    }
  }
}

// ---------------- fused aggregates: wave/node, 4 edges per iteration (uint4 lanes) ----------------
// layout: fl = lane&15 owns feats fl*8..fl*8+7 ; g4 = lane>>4 indexes edge-in-quad.

struct F8 { float v[8]; };

__device__ inline void acc_row(const uint4* __restrict__ P4, int s, int fl, bool valid, float* a) {
  uint4 u = P4[(size_t)s * 16 + fl];
  if (valid) {
    a[0] += bflo(u.x); a[1] += bfhi(u.x);
    a[2] += bflo(u.y); a[3] += bfhi(u.y);
    a[4] += bflo(u.z); a[5] += bfhi(u.z);
    a[6] += bflo(u.w); a[7] += bfhi(u.w);
  }
}

__device__ inline void gather_mean(const ushort* __restrict__ P, const int* __restrict__ rowptr,
                                   const int* __restrict__ srclist, int w, int lane, float* a) {
  const uint4* P4 = (const uint4*)P;
  int fl = lane & 15, g4 = lane >> 4;
  int beg = rowptr[w], end = rowptr[w + 1];
  for (int base = beg; base < end; base += 64) {
    int m = end - base;
    if (m > 64) m = 64;
    int sidx = (lane < m) ? srclist[base + lane] : 0;
    for (int i = 0; i < m; i += 4) {
      int j = i + g4;
      int s = __shfl(sidx, j, 64);
      acc_row(P4, s, fl, j < m, a);
    }
  }
#pragma unroll
  for (int k = 0; k < 8; ++k) {
    a[k] += __shfl_xor(a[k], 16, 64);
    a[k] += __shfl_xor(a[k], 32, 64);
  }
  float inv = 1.f / fmaxf((float)(end - beg), 1.f);
#pragma unroll
  for (int k = 0; k < 8; ++k) a[k] *= inv;
}

__device__ inline void ln_relu8(const float* h, const float* __restrict__ gamma, const float* __restrict__ beta,
                                int fl, float* o) {
  float sum = 0.f;
#pragma unroll
  for (int k = 0; k < 8; ++k) sum += h[k];
#pragma unroll
  for (int off = 1; off < 16; off <<= 1) sum += __shfl_xor(sum, off, 64);
  float mu = sum * (1.f / 128.f);
  float s2 = 0.f;
#pragma unroll
  for (int k = 0; k < 8; ++k) { float d = h[k] - mu; s2 += d * d; }
#pragma unroll
  for (int off = 1; off < 16; off <<= 1) s2 += __shfl_xor(s2, off, 64);
  float scale = rsqrtf(s2 * (1.f / 128.f) + LN_EPS);
  float4 g0 = *(const float4*)(gamma + fl * 8);
  float4 g1 = *(const float4*)(gamma + fl * 8 + 4);
  float4 b0 = *(const float4*)(beta + fl * 8);
  float4 b1 = *(const float4*)(beta + fl * 8 + 4);
  const float* g = &g0.x;  // contiguous f4 pairs
  float gg[8] = {g0.x, g0.y, g0.z, g0.w, g1.x, g1.y, g1.z, g1.w};
  float bb[8] = {b0.x, b0.y, b0.z, b0.w, b1.x, b1.y, b1.z, b1.w};
  (void)g;
#pragma unroll
  for (int k = 0; k < 8; ++k) o[k] = fmaxf((h[k] - mu) * scale * gg[k] + bb[k], 0.f);
}

__device__ inline uint4 pack8(const float* v) {
  uint4 u;
  u.x = (uint)f2bf(v[0]) | ((uint)f2bf(v[1]) << 16);
  u.y = (uint)f2bf(v[2]) | ((uint)f2bf(v[3]) << 16);
  u.z = (uint)f2bf(v[4]) | ((uint)f2bf(v[5]) << 16);
  u.w = (uint)f2bf(v[6]) | ((uint)f2bf(v[7]) << 16);
  return u;
}

// agg1: h1 = mean(P)+Q+b_l (bf16 out) ; r = relu(LN(h1)) (bf16 out)
__global__ __launch_bounds__(256) void k_agg1(const ushort* __restrict__ P, const ushort* __restrict__ Q,
                                              const int* __restrict__ rowptr, const int* __restrict__ srclist,
                                              const float* __restrict__ b_l, const float* __restrict__ gamma,
                                              const float* __restrict__ beta, ushort* __restrict__ H1,
                                              ushort* __restrict__ R, int n) {
  int w = (blockIdx.x * 256 + threadIdx.x) >> 6;
  int lane = threadIdx.x & 63;
  if (w >= n) return;
  int fl = lane & 15;
  float a[8] = {0.f, 0.f, 0.f, 0.f, 0.f, 0.f, 0.f, 0.f};
  gather_mean(P, rowptr, srclist, w, lane, a);
  uint4 qv = ((const uint4*)Q)[(size_t)w * 16 + fl];
  float4 bl0 = *(const float4*)(b_l + fl * 8);
  float4 bl1 = *(const float4*)(b_l + fl * 8 + 4);
  float q[8] = {bflo(qv.x), bfhi(qv.x), bflo(qv.y), bfhi(qv.y), bflo(qv.z), bfhi(qv.z), bflo(qv.w), bfhi(qv.w)};
  float bl[8] = {bl0.x, bl0.y, bl0.z, bl0.w, bl1.x, bl1.y, bl1.z, bl1.w};
  float h[8];
#pragma unroll
  for (int k = 0; k < 8; ++k) h[k] = a[k] + q[k] + bl[k];
  float r[8];
  ln_relu8(h, gamma, beta, fl, r);
  if (lane < 16) {
    ((uint4*)H1)[(size_t)w * 16 + fl] = pack8(h);
    ((uint4*)R)[(size_t)w * 16 + fl] = pack8(r);
  }
}

// agg2: o = relu(LN(mean(U)+V+b_l+h1)) (bf16 out)
__global__ __launch_bounds__(256) void k_agg2(const ushort* __restrict__ U, const ushort* __restrict__ V,
                                              const ushort* __restrict__ H1, const int* __restrict__ rowptr,
                                              const int* __restrict__ srclist, const float* __restrict__ b_l,
                                              const float* __restrict__ gamma, const float* __restrict__ beta,
                                              ushort* __restrict__ O, int n) {
  int w = (blockIdx.x * 256 + threadIdx.x) >> 6;
  int lane = threadIdx.x & 63;
  if (w >= n) return;
  int fl = lane & 15;
  float a[8] = {0.f, 0.f, 0.f, 0.f, 0.f, 0.f, 0.f, 0.f};
  gather_mean(U, rowptr, srclist, w, lane, a);
  uint4 vv = ((const uint4*)V)[(size_t)w * 16 + fl];
  uint4 hv = ((const uint4*)H1)[(size_t)w * 16 + fl];
  float4 bl0 = *(const float4*)(b_l + fl * 8);
  float4 bl1 = *(const float4*)(b_l + fl * 8 + 4);
  float vf[8] = {bflo(vv.x), bfhi(vv.x), bflo(vv.y), bfhi(vv.y), bflo(vv.z), bfhi(vv.z), bflo(vv.w), bfhi(vv.w)};
  float hf[8] = {bflo(hv.x), bfhi(hv.x), bflo(hv.y), bfhi(hv.y), bflo(hv.z), bfhi(hv.z), bflo(hv.w), bfhi(hv.w)};
  float bl[8] = {bl0.x, bl0.y, bl0.z, bl0.w, bl1.x, bl1.y, bl1.z, bl1.w};
  float h[8];
#pragma unroll
  for (int k = 0; k < 8; ++k) h[k] = a[k] + vf[k] + bl[k] + hf[k];
  float o[8];
  ln_relu8(h, gamma, beta, fl, o);
  if (lane < 16) ((uint4*)O)[(size_t)w * 16 + fl] = pack8(o);
}

// ---------------- launch ----------------

extern "C" void kernel_launch(void* const* d_in, const int* in_sizes, int n_in,
                              void* d_out, int out_size, void* d_ws, size_t ws_size,
                              hipStream_t stream) {
  const float* x = (const float*)d_in[0];
  const int* ei = (const int*)d_in[1];
  // d_in[2] = edge_attr: unused by the reference
  const float* W_ne = (const float*)d_in[3];
  const float* b_ne = (const float*)d_in[4];
  const float* W_l = (const float*)d_in[5];
  const float* b_l = (const float*)d_in[6];
  const float* W_r = (const float*)d_in[7];
  const float* gamma = (const float*)d_in[8];
  const float* beta = (const float*)d_in[9];
  const float* W_lin = (const float*)d_in[10];
  const float* b_lin = (const float*)d_in[11];
  float* out = (float*)d_out;

  const int N = in_sizes[0] / 128;
  const int E = in_sizes[1] / 2;

  char* p = (char*)d_ws;
  const size_t S2 = (size_t)N * 128 * sizeof(ushort);
  ushort* Abf = (ushort*)p;      p += S2;                        // Pp, later U
  ushort* Qbf = (ushort*)p;      p += S2;                        // Pq, later V
  ushort* H1bf = (ushort*)p;     p += S2;                        // h1
  ushort* Dbf = (ushort*)p;      p += S2;                        // r, later o
  ushort* xbf = (ushort*)p;      p += S2;                        // x cast
  ushort* WAt = (ushort*)p;      p += 128 * 128 * sizeof(ushort);
  ushort* WBt = (ushort*)p;      p += 128 * 128 * sizeof(ushort);
  ushort* Wlt = (ushort*)p;      p += 128 * 128 * sizeof(ushort);
  ushort* Wrt = (ushort*)p;      p += 128 * 128 * sizeof(ushort);
  ushort* Wlint = (ushort*)p;    p += 64 * 128 * sizeof(ushort);
  float* bA = (float*)p;         p += 128 * sizeof(float);
  float* bB = (float*)p;         p += 128 * sizeof(float);
  int* cnt = (int*)p;            p += (size_t)N * sizeof(int);
  int* incl = (int*)p;           p += (size_t)N * sizeof(int);
  int* rowptr = (int*)p;         p += ((size_t)N + 4) * sizeof(int);
  int* cursor = (int*)p;         p += (size_t)N * sizeof(int);
  int* bsums = (int*)p;          p += 1024 * sizeof(int);
  int* srclist = (int*)p;

  const int nbS = (N + 255) / 256;
  const int nbE = (E + 255) / 256;
  const int nbG = (N + 127) / 128;
  const int nbW = ((N * 64) + 255) / 256;
  const int nbC = (N * 16 + 40960 + 255) / 256;

  hipMemsetAsync(cnt, 0, (size_t)N * sizeof(int), stream);
  k_hist<<<nbE, 256, 0, stream>>>(ei, cnt, E);
  k_scan1<<<nbS, 256, 0, stream>>>(cnt, incl, bsums, N);
  k_scan2<<<1, 256, 0, stream>>>(bsums, nbS);
  k_scan3<<<nbS, 256, 0, stream>>>(incl, bsums, cnt, rowptr, cursor, N);
  k_fill<<<nbE, 256, 0, stream>>>(ei, cursor, srclist, E);
  k_prep<<<129, 256, 0, stream>>>(W_ne, b_ne, W_l, W_r, WAt, WBt, bA, bB);
  k_cast_all<<<nbC, 256, 0, stream>>>(x, W_l, W_r, W_lin, xbf, Wlt, Wrt, Wlint, N);

  k_gemm<128, ushort><<<dim3(nbG, 2), 256, 0, stream>>>(xbf, WAt, WBt, bA, bB, Abf, Qbf, N);
  k_agg1<<<nbW, 256, 0, stream>>>(Abf, Qbf, rowptr, srclist, b_l, gamma, beta, H1bf, Dbf, N);
  k_gemm<128, ushort><<<dim3(nbG, 2), 256, 0, stream>>>(Dbf, Wlt, Wrt, nullptr, nullptr, Abf, Qbf, N);
  k_agg2<<<nbW, 256, 0, stream>>>(Abf, Qbf, H1bf, rowptr, srclist, b_l, gamma, beta, Dbf, N);
  k_gemm<64, float><<<dim3(nbG, 1), 256, 0, stream>>>(Dbf, Wlint, Wlint, b_lin, b_lin, out, out, N);
}